// Round 2
// baseline (728.407 us; speedup 1.0000x reference)
//
#include <hip/hip_runtime.h>

#define BB 2048
#define NN 1024
#define PP 8
#define MM 8
#define DT2 1e-4f
#define EPSB 3e-4f

// ws layout (float offsets)
#define WS_SCORES 0
#define WS_AVGSUM (PP*BB*MM)          // [P][M] sum of scores over batch
#define WS_TOTAL  (WS_AVGSUM + 64)    // 1 float: global sum of mixed
#define WS_MEANS  (WS_AVGSUM + 128)   // [P][B]
#define WS_COMB   (WS_MEANS + PP*BB)  // [B][N] sum_p mixed
#define WS_XL64   (WS_COMB + BB*NN)   // [B][N] doubles (sparse: only borderline)

// ---------------------------------------------------------------- K1: xl = x @ W^T + b (f32)
__global__ __launch_bounds__(256) void k1_gemm(const float* __restrict__ x,
                                               const float* __restrict__ W,
                                               const float* __restrict__ bias,
                                               float* __restrict__ xl) {
  __shared__ float As[32][68];   // [k][row], padded
  __shared__ float Bs[32][68];   // [k][col]
  const int t  = threadIdx.x;
  const int nb = blockIdx.x * 64;   // output col tile
  const int bb = blockIdx.y * 64;   // output row tile
  const int lr = t >> 3;            // 0..31 staging row
  const int lk = (t & 7) << 2;      // 0..28 staging k
  const int r0 = (t >> 4) << 2;     // 0..60
  const int c0 = (t & 15) << 2;     // 0..60
  float acc[4][4] = {};
  const float* pa0 = x + (size_t)(bb + lr) * NN + lk;
  const float* pa1 = x + (size_t)(bb + lr + 32) * NN + lk;
  const float* pb0 = W + (size_t)(nb + lr) * NN + lk;
  const float* pb1 = W + (size_t)(nb + lr + 32) * NN + lk;

  for (int kk = 0; kk < NN; kk += 32) {
    float4 a0 = *(const float4*)(pa0 + kk);
    float4 a1 = *(const float4*)(pa1 + kk);
    float4 b0 = *(const float4*)(pb0 + kk);
    float4 b1 = *(const float4*)(pb1 + kk);
    __syncthreads();
    As[lk+0][lr] = a0.x; As[lk+1][lr] = a0.y; As[lk+2][lr] = a0.z; As[lk+3][lr] = a0.w;
    As[lk+0][lr+32] = a1.x; As[lk+1][lr+32] = a1.y; As[lk+2][lr+32] = a1.z; As[lk+3][lr+32] = a1.w;
    Bs[lk+0][lr] = b0.x; Bs[lk+1][lr] = b0.y; Bs[lk+2][lr] = b0.z; Bs[lk+3][lr] = b0.w;
    Bs[lk+0][lr+32] = b1.x; Bs[lk+1][lr+32] = b1.y; Bs[lk+2][lr+32] = b1.z; Bs[lk+3][lr+32] = b1.w;
    __syncthreads();
#pragma unroll
    for (int k = 0; k < 32; ++k) {
      const float4 av = *(const float4*)&As[k][r0];
      const float4 bv = *(const float4*)&Bs[k][c0];
      acc[0][0] += av.x*bv.x; acc[0][1] += av.x*bv.y; acc[0][2] += av.x*bv.z; acc[0][3] += av.x*bv.w;
      acc[1][0] += av.y*bv.x; acc[1][1] += av.y*bv.y; acc[1][2] += av.y*bv.z; acc[1][3] += av.y*bv.w;
      acc[2][0] += av.z*bv.x; acc[2][1] += av.z*bv.y; acc[2][2] += av.z*bv.z; acc[2][3] += av.z*bv.w;
      acc[3][0] += av.w*bv.x; acc[3][1] += av.w*bv.y; acc[3][2] += av.w*bv.z; acc[3][3] += av.w*bv.w;
    }
  }
  const float4 bias4 = *(const float4*)(bias + nb + c0);
#pragma unroll
  for (int i = 0; i < 4; ++i) {
    float4 v;
    v.x = acc[i][0] + bias4.x; v.y = acc[i][1] + bias4.y;
    v.z = acc[i][2] + bias4.z; v.w = acc[i][3] + bias4.w;
    *(float4*)(xl + (size_t)(bb + r0 + i) * NN + nb + c0) = v;
  }
}

// ---------------------------------------------------------------- K1b: f64 fixup of borderline xl elements
// For |xl-1| < EPSB: recompute the dot in f64 (wave-cooperative), store xl64,
// and nudge the f32 xl so (xl32 > 1.f) matches the f64 decision.
__global__ __launch_bounds__(256) void k1b_fix(const float* __restrict__ x,
                                               const float* __restrict__ W,
                                               const float* __restrict__ blin,
                                               float* __restrict__ xl,
                                               double* __restrict__ xl64) {
  const int idx  = blockIdx.x * 256 + threadIdx.x;
  const int lane = threadIdx.x & 63;
  const float v  = xl[idx];
  const bool bd  = fabsf(v - 1.f) < EPSB;
  unsigned long long mask = __ballot(bd);
  while (mask) {
    const int src = (int)__ffsll(mask) - 1;
    mask &= mask - 1;
    const int eidx = __shfl(idx, src);
    const int b = eidx >> 10, n = eidx & 1023;
    const float* xr = x + ((size_t)b << 10);
    const float* wr = W + ((size_t)n << 10);
    double s = 0.0;
#pragma unroll
    for (int j = 0; j < 16; ++j) {
      const int k = lane + (j << 6);
      s += (double)xr[k] * (double)wr[k];
    }
#pragma unroll
    for (int off = 32; off > 0; off >>= 1) s += __shfl_down(s, off);
    const double tot = __shfl(s, 0);
    if (lane == src) {
      const double xv = tot + (double)blin[n];
      xl64[eidx] = xv;
      const float old = xl[eidx];
      xl[eidx] = (xv > 1.0) ? fmaxf(old, __uint_as_float(0x3F800001u))
                            : fminf(old, 1.0f);
    }
  }
}

// ---------------------------------------------------------------- K2: scores = softmax(xl@Wsel^T + bsel), avgsum += scores
__global__ __launch_bounds__(256) void k2_scores(const float* __restrict__ xl,
                                                 const float* __restrict__ Wsel,
                                                 const float* __restrict__ bsel,
                                                 float* __restrict__ scores,
                                                 float* __restrict__ avgsum) {
  __shared__ float xs[16][132];
  __shared__ float wsT[128][68];   // [k][pm]
  __shared__ float logitsL[16][64];
  __shared__ float avgL[64];
  const int t  = threadIdx.x;
  const int b0 = blockIdx.x << 4;      // 16 rows per block
  if (t < 64) avgL[t] = 0.f;
  const int r  = t >> 4;               // 0..15 compute row
  const int cg = (t & 15) << 2;        // 0..60 compute col group
  const int xr = t >> 4, xk = (t & 15) << 3;
  const int wp = t >> 2, wk = (t & 3) << 5;
  float acc[4] = {0.f, 0.f, 0.f, 0.f};

  for (int kc = 0; kc < NN; kc += 128) {
    __syncthreads();
    const float4 v0 = *(const float4*)(xl + (size_t)(b0 + xr) * NN + kc + xk);
    const float4 v1 = *(const float4*)(xl + (size_t)(b0 + xr) * NN + kc + xk + 4);
    xs[xr][xk+0] = v0.x; xs[xr][xk+1] = v0.y; xs[xr][xk+2] = v0.z; xs[xr][xk+3] = v0.w;
    xs[xr][xk+4] = v1.x; xs[xr][xk+5] = v1.y; xs[xr][xk+6] = v1.z; xs[xr][xk+7] = v1.w;
#pragma unroll
    for (int j = 0; j < 8; ++j) {
      const int kl = wk + (j << 2);
      const float4 w = *(const float4*)(Wsel + (size_t)wp * NN + kc + kl);
      wsT[kl+0][wp] = w.x; wsT[kl+1][wp] = w.y; wsT[kl+2][wp] = w.z; wsT[kl+3][wp] = w.w;
    }
    __syncthreads();
#pragma unroll 8
    for (int k = 0; k < 128; ++k) {
      const float xa = xs[r][k];
      const float4 w = *(const float4*)&wsT[k][cg];
      acc[0] += xa*w.x; acc[1] += xa*w.y; acc[2] += xa*w.z; acc[3] += xa*w.w;
    }
  }
  logitsL[r][cg+0] = acc[0]; logitsL[r][cg+1] = acc[1];
  logitsL[r][cg+2] = acc[2]; logitsL[r][cg+3] = acc[3];
  __syncthreads();
  if (t < 128) {
    const int row = t >> 3, p = t & 7;
    float l[8], e[8];
    float mx = -1e30f;
#pragma unroll
    for (int m = 0; m < 8; ++m) {
      l[m] = logitsL[row][p*8+m] + bsel[p*8+m];
      mx = fmaxf(mx, l[m]);
    }
    float s = 0.f;
#pragma unroll
    for (int m = 0; m < 8; ++m) { e[m] = expf(l[m] - mx); s += e[m]; }
    const float inv = 1.f / s;
    float sc[8];
#pragma unroll
    for (int m = 0; m < 8; ++m) sc[m] = e[m] * inv;
    const size_t base = ((size_t)p * BB + b0 + row) * 8;
    float4 o0, o1;
    o0.x = sc[0]; o0.y = sc[1]; o0.z = sc[2]; o0.w = sc[3];
    o1.x = sc[4]; o1.y = sc[5]; o1.z = sc[6]; o1.w = sc[7];
    *(float4*)(scores + base)     = o0;
    *(float4*)(scores + base + 4) = o1;
#pragma unroll
    for (int m = 0; m < 8; ++m) atomicAdd(&avgL[p*8+m], sc[m]);
  }
  __syncthreads();
  if (t < 64) atomicAdd(&avgsum[t], avgL[t]);
}

// ---------------------------------------------------------------- K3: poly_mems writes + combined + means + total
__global__ __launch_bounds__(256) void k3_poly(const float* __restrict__ xl,
                                               const double* __restrict__ xl64,
                                               const float* __restrict__ Wf,
                                               const float* __restrict__ scores,
                                               const float* __restrict__ avgsum,
                                               const float* __restrict__ spring_k,
                                               const float* __restrict__ ms_thr,
                                               float* __restrict__ poly,
                                               float* __restrict__ combined,
                                               float* __restrict__ means,
                                               float* __restrict__ total) {
  __shared__ float WfL[PP*MM*256];     // 64 KB, [pm][256-wide n tile]
  __shared__ float scoresL[PP][4][MM];
  __shared__ float suppL[PP][4];
  __shared__ float coefL[PP];
  __shared__ float ldsTot;
  const int t    = threadIdx.x;
  const int bg0  = blockIdx.x << 2;    // 4 rows per block
  const int bl   = t >> 6;             // wave id == local row
  const int lane = t & 63;
  const int bg   = bg0 + bl;

  if (t == 0) ldsTot = 0.f;
  if (t < PP) coefL[t] = 0.5f * spring_k[t];
  if (t < 32) {
    const int p = t >> 2, bi = t & 3;
    float ss = 0.f;
#pragma unroll
    for (int m = 0; m < MM; ++m) {
      const float sc = scores[((size_t)p * BB + bg0 + bi) * 8 + m];
      scoresL[p][bi][m] = sc;
      const float av = avgsum[p*MM+m] * (1.f/2048.f);
      ss += (av > ms_thr[p]) ? sc * 0.1f : sc;
    }
    suppL[p][bi] = ss;
  }

  float cnt[PP] = {};
  for (int tile = 0; tile < 4; ++tile) {
    __syncthreads();
#pragma unroll
    for (int j = 0; j < 16; ++j) {
      const int f  = (j << 10) + (t << 2);
      const int pm = f >> 8, nl = f & 255;
      *(float4*)&WfL[f] = *(const float4*)(Wf + (size_t)pm * NN + (tile << 8) + nl);
    }
    __syncthreads();
    const int n0 = (tile << 8) + (lane << 2);
    const size_t ebase = (size_t)bg * NN + n0;
    const float4 xlv = *(const float4*)(xl + ebase);
    // borderline detection (rare): decisions need f64 near the threshold
    const bool bd0 = fabsf(xlv.x - 1.f) < EPSB;
    const bool bd1 = fabsf(xlv.y - 1.f) < EPSB;
    const bool bd2 = fabsf(xlv.z - 1.f) < EPSB;
    const bool bd3 = fabsf(xlv.w - 1.f) < EPSB;
    const bool anyb = bd0 | bd1 | bd2 | bd3;
    double x64[4];
    if (__builtin_expect(anyb, 0)) {
      if (bd0) x64[0] = xl64[ebase+0];
      if (bd1) x64[1] = xl64[ebase+1];
      if (bd2) x64[2] = xl64[ebase+2];
      if (bd3) x64[3] = xl64[ebase+3];
    }
    float4 comb = {0.f, 0.f, 0.f, 0.f};
#pragma unroll
    for (int p = 0; p < PP; ++p) {
      float4 eq = {0.f, 0.f, 0.f, 0.f};
#pragma unroll
      for (int m = 0; m < MM; ++m) {
        const float s = scoresL[p][bl][m];
        const float4 w = *(const float4*)&WfL[((p*MM + m) << 8) + (lane << 2)];
        eq.x += s*w.x; eq.y += s*w.y; eq.z += s*w.z; eq.w += s*w.w;
      }
      const float cp = coefL[p];
      float4 nx;
      nx.x = xlv.x - (cp * (xlv.x - eq.x)) * DT2;
      nx.y = xlv.y - (cp * (xlv.y - eq.y)) * DT2;
      nx.z = xlv.z - (cp * (xlv.z - eq.z)) * DT2;
      nx.w = xlv.w - (cp * (xlv.w - eq.w)) * DT2;
#pragma unroll
      for (int m = 0; m < MM; ++m) {
        *(float4*)(poly + ((size_t)(p*MM + m) * BB + bg) * NN + n0) = nx;
      }
      float4 spk;
      spk.x = nx.x > 1.f ? 1.f : 0.f;
      spk.y = nx.y > 1.f ? 1.f : 0.f;
      spk.z = nx.z > 1.f ? 1.f : 0.f;
      spk.w = nx.w > 1.f ? 1.f : 0.f;
      if (__builtin_expect(anyb, 0)) {
        const double cpd = (double)cp * (double)DT2;
        if (bd0) spk.x = (x64[0] - cpd*(x64[0] - (double)eq.x) > 1.0) ? 1.f : 0.f;
        if (bd1) spk.y = (x64[1] - cpd*(x64[1] - (double)eq.y) > 1.0) ? 1.f : 0.f;
        if (bd2) spk.z = (x64[2] - cpd*(x64[2] - (double)eq.z) > 1.0) ? 1.f : 0.f;
        if (bd3) spk.w = (x64[3] - cpd*(x64[3] - (double)eq.w) > 1.0) ? 1.f : 0.f;
      }
      cnt[p] += spk.x + spk.y + spk.z + spk.w;
      const float ss = suppL[p][bl];
      comb.x += ss*spk.x; comb.y += ss*spk.y; comb.z += ss*spk.z; comb.w += ss*spk.w;
    }
    *(float4*)(combined + ebase) = comb;
  }

#pragma unroll
  for (int p = 0; p < PP; ++p) {
    float c = cnt[p];
    for (int off = 32; off > 0; off >>= 1) c += __shfl_down(c, off);
    cnt[p] = c;   // valid on lane 0
  }
  if (lane == 0) {
    float rm = 0.f;
#pragma unroll
    for (int p = 0; p < PP; ++p) {
      const float ss = suppL[p][bl];
      means[(size_t)p * BB + bg] = ss * (cnt[p] * (1.f/1024.f));
      rm += ss * cnt[p];
    }
    atomicAdd(&ldsTot, rm);
  }
  __syncthreads();
  if (t == 0) atomicAdd(total, ldsTot);
}

// ---------------------------------------------------------------- K5: final output
__global__ __launch_bounds__(256) void k5_final(const float* __restrict__ xl,
                                                const float* __restrict__ combined,
                                                const float* __restrict__ means,
                                                const float* __restrict__ coupling,
                                                const float* __restrict__ g_inh,
                                                const float* __restrict__ total,
                                                float* __restrict__ out) {
  const int b = blockIdx.x;
  const int t = threadIdx.x;
  float cf = 0.f;
#pragma unroll
  for (int q = 0; q < PP; ++q) {
    float wq = 0.f;
#pragma unroll
    for (int p = 0; p < PP; ++p) wq += coupling[p*PP + q];
    cf += 0.125f * wq * means[(size_t)q * BB + b];
  }
  const float inh = g_inh[0] * total[0] * (1.f / (8.f * 2048.f * 1024.f));
  const float add = cf - inh;
  const int n0 = t << 2;
  const float4 xlv = *(const float4*)(xl + (size_t)b * NN + n0);
  const float4 cmb = *(const float4*)(combined + (size_t)b * NN + n0);
  float4 o;
  o.x = ((xlv.x > 1.f) ? 1.f : 0.f) + 0.125f*cmb.x + add;
  o.y = ((xlv.y > 1.f) ? 1.f : 0.f) + 0.125f*cmb.y + add;
  o.z = ((xlv.z > 1.f) ? 1.f : 0.f) + 0.125f*cmb.z + add;
  o.w = ((xlv.w > 1.f) ? 1.f : 0.f) + 0.125f*cmb.w + add;
  *(float4*)(out + (size_t)b * NN + n0) = o;
}

// ----------------------------------------------------------------
extern "C" void kernel_launch(void* const* d_in, const int* in_sizes, int n_in,
                              void* d_out, int out_size, void* d_ws, size_t ws_size,
                              hipStream_t stream) {
  const float* x        = (const float*)d_in[0];
  const float* W        = (const float*)d_in[1];
  const float* blin     = (const float*)d_in[2];
  const float* Wsel     = (const float*)d_in[3];
  const float* bsel     = (const float*)d_in[4];
  const float* Wf       = (const float*)d_in[5];
  const float* springk  = (const float*)d_in[6];
  // d_in[7] = damping_c (unused: first step has velocity = 0)
  const float* msthr    = (const float*)d_in[8];
  const float* coupling = (const float*)d_in[9];
  const float* ginh     = (const float*)d_in[10];

  float* out  = (float*)d_out;
  float* xl   = out + (size_t)BB * NN;        // reg_mem output slot == xl
  float* poly = out + (size_t)2 * BB * NN;    // poly_mems output slot

  float* ws       = (float*)d_ws;
  float* scores   = ws + WS_SCORES;
  float* avgsum   = ws + WS_AVGSUM;
  float* total    = ws + WS_TOTAL;
  float* means    = ws + WS_MEANS;
  float* combined = ws + WS_COMB;
  double* xl64    = (double*)(ws + WS_XL64);

  hipMemsetAsync(avgsum, 0, 128 * sizeof(float), stream);  // avgsum[64] + total

  hipLaunchKernelGGL(k1_gemm,  dim3(16, 32), dim3(256), 0, stream, x, W, blin, xl);
  hipLaunchKernelGGL(k1b_fix,  dim3(BB*NN/256), dim3(256), 0, stream, x, W, blin, xl, xl64);
  hipLaunchKernelGGL(k2_scores, dim3(128),   dim3(256), 0, stream, xl, Wsel, bsel, scores, avgsum);
  hipLaunchKernelGGL(k3_poly,   dim3(512),   dim3(256), 0, stream, xl, xl64, Wf, scores, avgsum,
                     springk, msthr, poly, combined, means, total);
  hipLaunchKernelGGL(k5_final,  dim3(2048),  dim3(256), 0, stream, xl, combined, means,
                     coupling, ginh, total, out);
}